// Round 2
// baseline (500.458 us; speedup 1.0000x reference)
//
#include <hip/hip_runtime.h>

#define DI __device__ __forceinline__

constexpr int AEV = 384;
constexpr int H1N = 160;
constexpr int H2N = 128;
constexpr int H3N = 96;
constexpr int NSP = 4;

// LDS row strides in halfs. All chosen so the l15-lane word-stride mod 32 gives a
// 2-way bank spread (free on CDNA4; same residue classes as the proven kernel):
constexpr int W1P  = 392;  // 196 words, l15*196%32 = l15*4 -> 2-way.  W1 FULL, resident.
constexpr int W2AP = 104;  //  52 words, l15*20%32 -> 2-way.           W2 k[0,96)
constexpr int W2BP = 72;   //  36 words, l15*4%32  -> 2-way.           W2 k[96,160)
constexpr int W3P  = 136;  //  68 words, l15*4%32  -> 2-way.           W3 full
constexpr int RH   = H1N * W1P;          // region R offset: 62720 halfs (125440 B)
constexpr int WSH  = RH + H2N * W2AP;    // 76032 halfs = 152064 B (R = max slab 13312 halfs)

using half8  = __attribute__((ext_vector_type(8))) _Float16;
using half4v = __attribute__((ext_vector_type(4))) _Float16;
using f32x4  = __attribute__((ext_vector_type(4))) float;

// Pre-transposed fp16 weights, [species][neuron][k] (753 KB)
__device__ __align__(16) _Float16 g_w1[NSP * H1N * AEV];
__device__ __align__(16) _Float16 g_w2[NSP * H2N * H1N];
__device__ __align__(16) _Float16 g_w3[NSP * H3N * H2N];

DI float celu_f(float x) {   // celu(x,0.1) = max(x,0)+0.1*(exp(min(x,0)/0.1)-1)
  return fmaxf(x, 0.f) + 0.1f * (exp2f(fminf(x, 0.f) * 14.426950408889634f) - 1.f);
}
DI f32x4 mfma16h(half8 a, half8 b, f32x4 c) {
  return __builtin_amdgcn_mfma_f32_16x16x32_f16(a, b, c, 0, 0, 0);
}
DI half8 cvt8(f32x4 a, f32x4 b) {
  half8 t;
  t[0] = (_Float16)a[0]; t[1] = (_Float16)a[1]; t[2] = (_Float16)a[2]; t[3] = (_Float16)a[3];
  t[4] = (_Float16)b[0]; t[5] = (_Float16)b[1]; t[6] = (_Float16)b[2]; t[7] = (_Float16)b[3];
  return t;
}
DI half4v shfl4(half4v v, int src) {
  union { half4v h; int i[2]; } u;
  u.h = v;
  u.i[0] = __shfl(u.i[0], src, 64);
  u.i[1] = __shfl(u.i[1], src, 64);
  return u.h;
}
// Build B-fragment slab ks for next layer from C-layout regs hb[] (unchanged, verified).
DI half8 bfrag(const half4v* hb, int ks, int l15, int quad) {
  const int sLo = (quad & 1) * 32 + l15, sHi = sLo + 16;
  half4v loA = shfl4(hb[2 * ks], sLo),     loB = shfl4(hb[2 * ks + 1], sLo);
  half4v hiA = shfl4(hb[2 * ks], sHi),     hiB = shfl4(hb[2 * ks + 1], sHi);
  half4v lo = (quad & 2) ? loB : loA;
  half4v hi = (quad & 2) ? hiB : hiA;
  half8 b;
  b[0] = lo[0]; b[1] = lo[1]; b[2] = lo[2]; b[3] = lo[3];
  b[4] = hi[0]; b[5] = hi[1]; b[6] = hi[2]; b[7] = hi[3];
  return b;
}
// Non-temporal aev load (ext-vector type: __builtin_nontemporal_load rejects HIP float4):
// 307 MB streamed once/iter must not evict the L2/L3-resident weights.
DI f32x4 ntl4(const float* p) { return __builtin_nontemporal_load((const f32x4*)p); }

// ---------------- prologue: transpose to [s][n][k] fp16, fused for 3 layers ----
template <int K, int N>
DI void tp(const float* __restrict__ src, _Float16* dst, int id) {
  constexpr int per = K * N;
  int s = id / per, r = id % per;
  int n = r / K, k = r % K;
  dst[s * per + n * K + k] = (_Float16)src[s * per + k * N + n];
}

__global__ void prep(const float* __restrict__ W1, const float* __restrict__ W2,
                     const float* __restrict__ W3, float* __restrict__ out) {
  int id = blockIdx.x * 256 + threadIdx.x;
  if (id == 0) out[0] = 0.f;
  constexpr int E1 = NSP * AEV * H1N;
  constexpr int E2 = NSP * H1N * H2N;
  constexpr int E3 = NSP * H2N * H3N;
  if (id < E1)                 tp<AEV, H1N>(W1, g_w1, id);
  else if (id < E1 + E2)       tp<H1N, H2N>(W2, g_w2, id - E1);
  else if (id < E1 + E2 + E3)  tp<H2N, H3N>(W3, g_w3, id - E1 - E2);
}

// ---------------- fused MLP: persistent-W1 blocks, 1 block/CU, 6-7 tiles each ----
// 152 KB LDS => 1 block/CU (8 waves, 2/SIMD) => VGPR cap 256; W1 staged ONCE per block,
// layer 1 runs all 12 K-slabs with zero barriers and a 4-deep aev register pipeline.
__global__ __launch_bounds__(512, 2) void fused_mlp(
    const float* __restrict__ aev,
    const float* __restrict__ b1, const float* __restrict__ b2,
    const float* __restrict__ b3,
    const float* __restrict__ W4, const float* __restrict__ pb4,
    const int* __restrict__ i0, const int* __restrict__ i1,
    const int* __restrict__ i2, const int* __restrict__ i3,
    int chunk, float* __restrict__ out) {
  __shared__ __align__(16) _Float16 WS[WSH];   // 152064 B: W1 resident | region R (W2A/W2B/W3)
  __shared__ float RED[8];

  const int tid  = threadIdx.x;
  const int lane = tid & 63, wav = tid >> 6;
  const int l15  = lane & 15, quad = lane >> 4;
  const int s    = blockIdx.y;
  const int* idx = (s == 0) ? i0 : (s == 1) ? i1 : (s == 2) ? i2 : i3;
  const int ntiles = (chunk + 127) >> 7;

  const _Float16* w1src = g_w1 + (size_t)s * H1N * AEV;
  const _Float16* w2src = g_w2 + (size_t)s * H2N * H1N;
  const _Float16* w3src = g_w3 + (size_t)s * H3N * H2N;

  // ---- stage FULL W1 once (160 rows x 48 half8 = 7680 = 15*512 exact)
#pragma unroll
  for (int i = 0; i < 15; ++i) {
    int c = tid + i * 512;
    int n = c / 48, kc = c % 48;
    *(half8*)(WS + n * W1P + kc * 8) = *(const half8*)(w1src + n * AEV + kc * 8);
  }

  // ---- first-tile row pointer + 4-deep aev prefetch (issued under the W1 drain)
  int t = blockIdx.x;                        // tiles t, t+64, t+128, ...
  bool valid;
  const float* xr;
  {
    int a = t * 128 + wav * 16 + l15;        // species-local atom
    valid = (a < chunk);
    int r = idx[valid ? a : (chunk - 1)];
    xr = aev + (size_t)r * AEV + quad * 8;
  }
  f32x4 pA0 = ntl4(xr),      pB0 = ntl4(xr + 4);
  f32x4 pA1 = ntl4(xr + 32), pB1 = ntl4(xr + 36);
  f32x4 pA2 = ntl4(xr + 64), pB2 = ntl4(xr + 68);
  f32x4 pA3 = ntl4(xr + 96), pB3 = ntl4(xr + 100);

  float bsum = 0.f;
  __syncthreads();

  for (; t < ntiles; t += 64) {
    // ---------------- Layer 1 (K=384): W1 resident -> barrier-free, depth-4 pipeline
    f32x4 acc[10];
#pragma unroll
    for (int m = 0; m < 10; ++m)
#pragma unroll
      for (int i = 0; i < 4; ++i) acc[m][i] = 0.f;
#pragma unroll
    for (int ks = 0; ks < 12; ++ks) {
      half8 bv = cvt8(pA0, pB0);
      pA0 = pA1; pB0 = pB1; pA1 = pA2; pB1 = pB2; pA2 = pA3; pB2 = pB3;
      if (ks < 8) {                          // keep 4 slab-pairs in flight (counted vmcnt)
        pA3 = ntl4(xr + (ks + 4) * 32);
        pB3 = ntl4(xr + (ks + 4) * 32 + 4);
      }
#pragma unroll
      for (int mt = 0; mt < 10; ++mt) {
        half8 aw = *(const half8*)(WS + (mt * 16 + l15) * W1P + ks * 32 + quad * 8);
        acc[mt] = mfma16h(aw, bv, acc[mt]);
      }
    }
    half4v hb[10];
#pragma unroll
    for (int mt = 0; mt < 10; ++mt) {
      float4 bb = *(const float4*)(b1 + s * H1N + mt * 16 + quad * 4);
      half4v o;
      o[0] = (_Float16)celu_f(acc[mt][0] + bb.x);
      o[1] = (_Float16)celu_f(acc[mt][1] + bb.y);
      o[2] = (_Float16)celu_f(acc[mt][2] + bb.z);
      o[3] = (_Float16)celu_f(acc[mt][3] + bb.w);
      hb[mt] = o;
    }

    // ---------------- stage W2 slab A (split load/store) + next-tile aev pre-issue.
    // Order matters for in-order vmcnt: W2A L2-loads first, then the 8 HBM pre-pairs
    // (newer, so the ds_writes wait only vmcnt(8)); the barrier drain then doubles as
    // the HBM transfer window that would otherwise be an idle bubble during L2/L3.
    bool v2;
    const float* xr2;
    {
      int a2 = (t + 64) * 128 + wav * 16 + l15;
      v2 = (a2 < chunk);                     // also false when t+64 >= ntiles
      int r2 = idx[v2 ? a2 : (chunk - 1)];
      xr2 = aev + (size_t)r2 * AEV + quad * 8;
    }
    const int nA0 = tid / 12,          kA0 = tid % 12;            // 128*12 = 1536 = 3*512
    const int nA1 = (tid + 512) / 12,  kA1 = (tid + 512) % 12;
    const int nA2 = (tid + 1024) / 12, kA2 = (tid + 1024) % 12;
    half8 sA0 = *(const half8*)(w2src + nA0 * H1N + kA0 * 8);
    half8 sA1 = *(const half8*)(w2src + nA1 * H1N + kA1 * 8);
    half8 sA2 = *(const half8*)(w2src + nA2 * H1N + kA2 * 8);
    pA0 = ntl4(xr2);      pB0 = ntl4(xr2 + 4);       // next tile ks0..3
    pA1 = ntl4(xr2 + 32); pB1 = ntl4(xr2 + 36);
    pA2 = ntl4(xr2 + 64); pB2 = ntl4(xr2 + 68);
    pA3 = ntl4(xr2 + 96); pB3 = ntl4(xr2 + 100);
    *(half8*)(WS + RH + nA0 * W2AP + kA0 * 8) = sA0;  // R last read before prev RED barrier
    *(half8*)(WS + RH + nA1 * W2AP + kA1 * 8) = sA1;
    *(half8*)(WS + RH + nA2 * W2AP + kA2 * 8) = sA2;
    __syncthreads();

    // ---------------- Layer 2, k[0,96)
    f32x4 acc2[8];
#pragma unroll
    for (int m = 0; m < 8; ++m)
#pragma unroll
      for (int i = 0; i < 4; ++i) acc2[m][i] = 0.f;
#pragma unroll
    for (int ks = 0; ks < 3; ++ks) {
      half8 bv = bfrag(hb, ks, l15, quad);
#pragma unroll
      for (int mt = 0; mt < 8; ++mt) {
        half8 aw = *(const half8*)(WS + RH + (mt * 16 + l15) * W2AP + ks * 32 + quad * 8);
        acc2[mt] = mfma16h(aw, bv, acc2[mt]);
      }
    }
    // stage W2 slab B: loads now (overlap/drain at barrier), stores after read-drain
    const int nB0 = tid / 8,         kB0 = tid % 8;               // 128*8 = 1024 = 2*512
    const int nB1 = (tid + 512) / 8, kB1 = (tid + 512) % 8;
    half8 sB0 = *(const half8*)(w2src + 96 + nB0 * H1N + kB0 * 8);
    half8 sB1 = *(const half8*)(w2src + 96 + nB1 * H1N + kB1 * 8);
    __syncthreads();                         // everyone done reading slab A
    *(half8*)(WS + RH + nB0 * W2BP + kB0 * 8) = sB0;
    *(half8*)(WS + RH + nB1 * W2BP + kB1 * 8) = sB1;
    __syncthreads();

    // ---------------- Layer 2, k[96,160)
#pragma unroll
    for (int ks = 3; ks < 5; ++ks) {
      half8 bv = bfrag(hb, ks, l15, quad);
#pragma unroll
      for (int mt = 0; mt < 8; ++mt) {
        half8 aw = *(const half8*)(WS + RH + (mt * 16 + l15) * W2BP + (ks - 3) * 32 + quad * 8);
        acc2[mt] = mfma16h(aw, bv, acc2[mt]);
      }
    }
    half4v hb2[8];
#pragma unroll
    for (int mt = 0; mt < 8; ++mt) {
      float4 bb = *(const float4*)(b2 + s * H2N + mt * 16 + quad * 4);
      half4v o;
      o[0] = (_Float16)celu_f(acc2[mt][0] + bb.x);
      o[1] = (_Float16)celu_f(acc2[mt][1] + bb.y);
      o[2] = (_Float16)celu_f(acc2[mt][2] + bb.z);
      o[3] = (_Float16)celu_f(acc2[mt][3] + bb.w);
      hb2[mt] = o;
    }
    // stage W3 (full): loads now, stores after read-drain barrier
    const int nC0 = tid / 16,          kC0 = tid % 16;            // 96*16 = 1536 = 3*512
    const int nC1 = (tid + 512) / 16,  kC1 = (tid + 512) % 16;
    const int nC2 = (tid + 1024) / 16, kC2 = (tid + 1024) % 16;
    half8 sC0 = *(const half8*)(w3src + nC0 * H2N + kC0 * 8);
    half8 sC1 = *(const half8*)(w3src + nC1 * H2N + kC1 * 8);
    half8 sC2 = *(const half8*)(w3src + nC2 * H2N + kC2 * 8);
    __syncthreads();                         // done reading W2 slab B
    *(half8*)(WS + RH + nC0 * W3P + kC0 * 8) = sC0;
    *(half8*)(WS + RH + nC1 * W3P + kC1 * 8) = sC1;
    *(half8*)(WS + RH + nC2 * W3P + kC2 * 8) = sC2;
    __syncthreads();

    // ---------------- Layer 3 (K=128)
    f32x4 acc3[6];
#pragma unroll
    for (int m = 0; m < 6; ++m)
#pragma unroll
      for (int i = 0; i < 4; ++i) acc3[m][i] = 0.f;
#pragma unroll
    for (int ks = 0; ks < 4; ++ks) {
      half8 bv = bfrag(hb2, ks, l15, quad);
#pragma unroll
      for (int mt = 0; mt < 6; ++mt) {
        half8 aw = *(const half8*)(WS + RH + (mt * 16 + l15) * W3P + ks * 32 + quad * 8);
        acc3[mt] = mfma16h(aw, bv, acc3[mt]);
      }
    }

    // ---------------- Layer 4 + per-tile block reduce (current tile's `valid`)
    float e = 0.f;
#pragma unroll
    for (int mt = 0; mt < 6; ++mt) {
      float4 bb = *(const float4*)(b3 + s * H3N + mt * 16 + quad * 4);
      float4 wv = *(const float4*)(W4 + s * H3N + mt * 16 + quad * 4);
      e += (float)(_Float16)celu_f(acc3[mt][0] + bb.x) * wv.x
         + (float)(_Float16)celu_f(acc3[mt][1] + bb.y) * wv.y
         + (float)(_Float16)celu_f(acc3[mt][2] + bb.z) * wv.z
         + (float)(_Float16)celu_f(acc3[mt][3] + bb.w) * wv.w;
    }
    e += __shfl_xor(e, 16, 64);
    e += __shfl_xor(e, 32, 64);              // lanes sharing l15 now hold the atom's dot
    e = (lane < 16 && valid) ? (e + pb4[s]) : 0.f;
#pragma unroll
    for (int off = 1; off < 64; off <<= 1) e += __shfl_xor(e, off, 64);
    if (lane == 0) RED[wav] = e;
    __syncthreads();                         // also fences R reads before next W2A stores
    if (tid == 0) {
      float ts = 0.f;
#pragma unroll
      for (int i = 0; i < 8; ++i) ts += RED[i];
      bsum += ts;
    }
    valid = v2;                              // rotate next-tile state
    xr = xr2;
  }
  if (tid == 0) atomicAdd(out, bsum);
}

extern "C" void kernel_launch(void* const* d_in, const int* in_sizes, int n_in,
                              void* d_out, int out_size, void* d_ws, size_t ws_size,
                              hipStream_t stream) {
  (void)n_in; (void)d_ws; (void)ws_size; (void)out_size;
  const float* aev = (const float*)d_in[0];
  const float* W1  = (const float*)d_in[1];
  const float* b1  = (const float*)d_in[2];
  const float* W2  = (const float*)d_in[3];
  const float* b2  = (const float*)d_in[4];
  const float* W3  = (const float*)d_in[5];
  const float* b3  = (const float*)d_in[6];
  const float* W4  = (const float*)d_in[7];
  const float* b4  = (const float*)d_in[8];
  const int* iH = (const int*)d_in[9];
  const int* iC = (const int*)d_in[10];
  const int* iN = (const int*)d_in[11];
  const int* iO = (const int*)d_in[12];
  const int chunk = in_sizes[9];

  constexpr int TOT = NSP * (AEV * H1N + H1N * H2N + H2N * H3N);  // 376832 = 1472*256
  prep<<<TOT / 256, 256, 0, stream>>>(W1, W2, W3, (float*)d_out);

  // 256 persistent blocks: 1/CU (152 KB LDS), 64 blocks/species, 6-7 tiles each
  fused_mlp<<<dim3(64, NSP), 512, 0, stream>>>(aev, b1, b2, b3, W4, b4,
                                               iH, iC, iN, iO, chunk, (float*)d_out);
}

// Round 3
// 472.478 us; speedup vs baseline: 1.0592x; 1.0592x over previous
//
#include <hip/hip_runtime.h>

#define DI __device__ __forceinline__

constexpr int AEV = 384;
constexpr int H1N = 160;
constexpr int H2N = 128;
constexpr int H3N = 96;
constexpr int NSP = 4;
constexpr int W1P = 200;   // W1 K-half LDS row stride (halfs): 100 words, l15*100%32=l15*4 -> 2-way (free)
constexpr int W2P = 168;   // W2 LDS row stride: 84 words, l15*20%32 -> 2-way
constexpr int W3P = 136;   // W3 LDS row stride: 68 words, l15*4%32  -> 2-way
constexpr int W3OFF = H2N * W2P;            // 21504 halfs; W2+W3 = 34560 halfs = 69120 B

using half8  = __attribute__((ext_vector_type(8))) _Float16;
using half4v = __attribute__((ext_vector_type(4))) _Float16;
using f32x4  = __attribute__((ext_vector_type(4))) float;

// Pre-transposed fp16 weights, [species][neuron][k] (753 KB, L2-resident)
__device__ __align__(16) _Float16 g_w1[NSP * H1N * AEV];
__device__ __align__(16) _Float16 g_w2[NSP * H2N * H1N];
__device__ __align__(16) _Float16 g_w3[NSP * H3N * H2N];

DI float celu_f(float x) {   // celu(x,0.1) = max(x,0)+0.1*(exp(min(x,0)/0.1)-1)
  return fmaxf(x, 0.f) + 0.1f * (exp2f(fminf(x, 0.f) * 14.426950408889634f) - 1.f);
}
DI f32x4 mfma16h(half8 a, half8 b, f32x4 c) {
  return __builtin_amdgcn_mfma_f32_16x16x32_f16(a, b, c, 0, 0, 0);
}
DI half8 cvt8(f32x4 a, f32x4 b) {
  half8 t;
  t[0] = (_Float16)a[0]; t[1] = (_Float16)a[1]; t[2] = (_Float16)a[2]; t[3] = (_Float16)a[3];
  t[4] = (_Float16)b[0]; t[5] = (_Float16)b[1]; t[6] = (_Float16)b[2]; t[7] = (_Float16)b[3];
  return t;
}
DI half4v shfl4(half4v v, int src) {
  union { half4v h; int i[2]; } u;
  u.h = v;
  u.i[0] = __shfl(u.i[0], src, 64);
  u.i[1] = __shfl(u.i[1], src, 64);
  return u.h;
}
// Build B-fragment slab ks for next layer from C-layout regs hb[]:
// dest lane (l15=atom, quad) needs H[k=ks*32+quad*8+j][atom], living in
// hb[2ks+(quad>>1)] of lanes ((quad&1)*32 + l15) [lo] and (+16) [hi].
DI half8 bfrag(const half4v* hb, int ks, int l15, int quad) {
  const int sLo = (quad & 1) * 32 + l15, sHi = sLo + 16;
  half4v loA = shfl4(hb[2 * ks], sLo),     loB = shfl4(hb[2 * ks + 1], sLo);
  half4v hiA = shfl4(hb[2 * ks], sHi),     hiB = shfl4(hb[2 * ks + 1], sHi);
  half4v lo = (quad & 2) ? loB : loA;
  half4v hi = (quad & 2) ? hiB : hiA;
  half8 b;
  b[0] = lo[0]; b[1] = lo[1]; b[2] = lo[2]; b[3] = lo[3];
  b[4] = hi[0]; b[5] = hi[1]; b[6] = hi[2]; b[7] = hi[3];
  return b;
}
// Non-temporal aev load (ext-vector: __builtin_nontemporal_load rejects HIP float4).
// The 307 MB aev stream is read exactly once per iteration; NT keeps it from evicting
// the L2-resident weights (753 KB) that every tile re-stages.
DI f32x4 ntl4(const float* p) { return __builtin_nontemporal_load((const f32x4*)p); }

// ---------------- prologue: transpose to [s][n][k] fp16, fused for 3 layers ----
template <int K, int N>
DI void tp(const float* __restrict__ src, _Float16* dst, int id) {
  constexpr int per = K * N;
  int s = id / per, r = id % per;
  int n = r / K, k = r % K;
  dst[s * per + n * K + k] = (_Float16)src[s * per + k * N + n];
}

__global__ void prep(const float* __restrict__ W1, const float* __restrict__ W2,
                     const float* __restrict__ W3, float* __restrict__ out) {
  int id = blockIdx.x * 256 + threadIdx.x;
  if (id == 0) out[0] = 0.f;
  constexpr int E1 = NSP * AEV * H1N;
  constexpr int E2 = NSP * H1N * H2N;
  constexpr int E3 = NSP * H2N * H3N;
  if (id < E1)                 tp<AEV, H1N>(W1, g_w1, id);
  else if (id < E1 + E2)       tp<H1N, H2N>(W2, g_w2, id - E1);
  else if (id < E1 + E2 + E3)  tp<H2N, H3N>(W3, g_w3, id - E1 - E2);
}

// ---------------- fused MLP: all activations in registers; LDS = weights only ----
// 69 KB LDS, __launch_bounds__(512,4) => 2 blocks/CU: one block's L1 gather (HBM)
// overlaps the other's L2/L3/L4 phases (LDS/VALU) — this overlap is load-bearing.
__global__ __launch_bounds__(512, 4) void fused_mlp(
    const float* __restrict__ aev,
    const float* __restrict__ b1, const float* __restrict__ b2,
    const float* __restrict__ b3,
    const float* __restrict__ W4, const float* __restrict__ pb4,
    const int* __restrict__ i0, const int* __restrict__ i1,
    const int* __restrict__ i2, const int* __restrict__ i3,
    int chunk, float* __restrict__ out) {
  __shared__ __align__(16) _Float16 WS[34560];   // 69120 B: W1-half | later W2+W3
  __shared__ float RED[8];

  const int tid  = threadIdx.x;
  const int lane = tid & 63, wav = tid >> 6;
  const int l15  = lane & 15, quad = lane >> 4;
  const int s    = blockIdx.y;
  const int* idx = (s == 0) ? i0 : (s == 1) ? i1 : (s == 2) ? i2 : i3;

  const int a = blockIdx.x * 128 + wav * 16 + l15;     // species-local atom
  const bool valid = (a < chunk);
  const int r = idx[valid ? a : (chunk - 1)];
  const float* xr = aev + (size_t)r * AEV + quad * 8;

  const _Float16* w1src = g_w1 + (size_t)s * H1N * AEV;

  // ---- stage W1 K-half 0 (k=0..191), stride W1P
#pragma unroll
  for (int i = 0; i < 8; ++i) {
    int c = tid + i * 512;
    if (c < H1N * 24) {
      int n = c / 24, kc = c % 24;
      *(half8*)(WS + n * W1P + kc * 8) = *(const half8*)(w1src + n * AEV + kc * 8);
    }
  }
  __syncthreads();

  // ---- Layer 1 (K=384 split 2x192), aev slab prefetch keeps HBM busy across barriers
  f32x4 acc[10];
#pragma unroll
  for (int m = 0; m < 10; ++m)
#pragma unroll
    for (int i = 0; i < 4; ++i) acc[m][i] = 0.f;

  f32x4 xf0 = ntl4(xr), xf1 = ntl4(xr + 4);
#pragma unroll
  for (int ks = 0; ks < 6; ++ks) {
    half8 bv = cvt8(xf0, xf1);
    xf0 = ntl4(xr + (ks + 1) * 32);                   // prefetch (ks=5 pulls half-1's first slab)
    xf1 = ntl4(xr + (ks + 1) * 32 + 4);
#pragma unroll
    for (int mt = 0; mt < 10; ++mt) {
      half8 aw = *(const half8*)(WS + (mt * 16 + l15) * W1P + ks * 32 + quad * 8);
      acc[mt] = mfma16h(aw, bv, acc[mt]);
    }
  }
  __syncthreads();                                     // done reading half 0
#pragma unroll
  for (int i = 0; i < 8; ++i) {                        // stage K-half 1 (k=192..383)
    int c = tid + i * 512;
    if (c < H1N * 24) {
      int n = c / 24, kc = c % 24;
      *(half8*)(WS + n * W1P + kc * 8) = *(const half8*)(w1src + 192 + n * AEV + kc * 8);
    }
  }
  __syncthreads();
#pragma unroll
  for (int ks = 6; ks < 12; ++ks) {
    half8 bv = cvt8(xf0, xf1);
    if (ks < 11) {
      xf0 = ntl4(xr + (ks + 1) * 32);
      xf1 = ntl4(xr + (ks + 1) * 32 + 4);
    }
#pragma unroll
    for (int mt = 0; mt < 10; ++mt) {
      half8 aw = *(const half8*)(WS + (mt * 16 + l15) * W1P + (ks - 6) * 32 + quad * 8);
      acc[mt] = mfma16h(aw, bv, acc[mt]);
    }
  }
  // epilogue in regs: hb[mt][i] = H1[n=mt*16+quad*4+i][atom=l15]
  half4v hb[10];
#pragma unroll
  for (int mt = 0; mt < 10; ++mt) {
    float4 bb = *(const float4*)(b1 + s * H1N + mt * 16 + quad * 4);
    half4v o;
    o[0] = (_Float16)celu_f(acc[mt][0] + bb.x);
    o[1] = (_Float16)celu_f(acc[mt][1] + bb.y);
    o[2] = (_Float16)celu_f(acc[mt][2] + bb.z);
    o[3] = (_Float16)celu_f(acc[mt][3] + bb.w);
    hb[mt] = o;
  }

  // ---- T14-lite: issue W2+W3 staging loads NOW (acc dead, only +32 VGPRs live);
  // their L2 latency drains under the next barrier's natural vmcnt(0) wait.
  const _Float16* w2src = g_w2 + (size_t)s * H2N * H1N;
  const _Float16* w3src = g_w3 + (size_t)s * H3N * H2N;
  half8 sW0 = *(const half8*)(w2src + (tid / 20) * H1N + (tid % 20) * 8);
  half8 sW1 = *(const half8*)(w2src + ((tid + 512) / 20) * H1N + ((tid + 512) % 20) * 8);
  half8 sW2 = *(const half8*)(w2src + ((tid + 1024) / 20) * H1N + ((tid + 1024) % 20) * 8);
  half8 sW3 = *(const half8*)(w2src + ((tid + 1536) / 20) * H1N + ((tid + 1536) % 20) * 8);
  half8 sW4 = *(const half8*)(w2src + ((tid + 2048) / 20) * H1N + ((tid + 2048) % 20) * 8);
  half8 sV0 = *(const half8*)(w3src + (tid / 16) * H2N + (tid % 16) * 8);
  half8 sV1 = *(const half8*)(w3src + ((tid + 512) / 16) * H2N + ((tid + 512) % 16) * 8);
  half8 sV2 = *(const half8*)(w3src + ((tid + 1024) / 16) * H2N + ((tid + 1024) % 16) * 8);

  __syncthreads();                                     // done reading W1 half 1
  // stores only — the loads above already landed (or land under this barrier's drain)
  *(half8*)(WS + (tid / 20) * W2P + (tid % 20) * 8) = sW0;
  *(half8*)(WS + ((tid + 512) / 20) * W2P + ((tid + 512) % 20) * 8) = sW1;
  *(half8*)(WS + ((tid + 1024) / 20) * W2P + ((tid + 1024) % 20) * 8) = sW2;
  *(half8*)(WS + ((tid + 1536) / 20) * W2P + ((tid + 1536) % 20) * 8) = sW3;
  *(half8*)(WS + ((tid + 2048) / 20) * W2P + ((tid + 2048) % 20) * 8) = sW4;
  *(half8*)(WS + W3OFF + (tid / 16) * W3P + (tid % 16) * 8) = sV0;
  *(half8*)(WS + W3OFF + ((tid + 512) / 16) * W3P + ((tid + 512) % 16) * 8) = sV1;
  *(half8*)(WS + W3OFF + ((tid + 1024) / 16) * W3P + ((tid + 1024) % 16) * 8) = sV2;
  __syncthreads();

  // ---- Layer 2 (K=160): B-frags via shfl from hb
  f32x4 acc2[8];
#pragma unroll
  for (int m = 0; m < 8; ++m)
#pragma unroll
    for (int i = 0; i < 4; ++i) acc2[m][i] = 0.f;
#pragma unroll
  for (int ks = 0; ks < 5; ++ks) {
    half8 bv = bfrag(hb, ks, l15, quad);
#pragma unroll
    for (int mt = 0; mt < 8; ++mt) {
      half8 aw = *(const half8*)(WS + (mt * 16 + l15) * W2P + ks * 32 + quad * 8);
      acc2[mt] = mfma16h(aw, bv, acc2[mt]);
    }
  }
  half4v hb2[8];
#pragma unroll
  for (int mt = 0; mt < 8; ++mt) {
    float4 bb = *(const float4*)(b2 + s * H2N + mt * 16 + quad * 4);
    half4v o;
    o[0] = (_Float16)celu_f(acc2[mt][0] + bb.x);
    o[1] = (_Float16)celu_f(acc2[mt][1] + bb.y);
    o[2] = (_Float16)celu_f(acc2[mt][2] + bb.z);
    o[3] = (_Float16)celu_f(acc2[mt][3] + bb.w);
    hb2[mt] = o;
  }

  // ---- Layer 3 (K=128)
  f32x4 acc3[6];
#pragma unroll
  for (int m = 0; m < 6; ++m)
#pragma unroll
    for (int i = 0; i < 4; ++i) acc3[m][i] = 0.f;
#pragma unroll
  for (int ks = 0; ks < 4; ++ks) {
    half8 bv = bfrag(hb2, ks, l15, quad);
#pragma unroll
    for (int mt = 0; mt < 6; ++mt) {
      half8 aw = *(const half8*)(WS + W3OFF + (mt * 16 + l15) * W3P + ks * 32 + quad * 8);
      acc3[mt] = mfma16h(aw, bv, acc3[mt]);
    }
  }

  // ---- Layer 4: per-lane partial dot over its (quad,i) neurons, then lane reduce
  float e = 0.f;
#pragma unroll
  for (int mt = 0; mt < 6; ++mt) {
    float4 bb = *(const float4*)(b3 + s * H3N + mt * 16 + quad * 4);
    float4 wv = *(const float4*)(W4 + s * H3N + mt * 16 + quad * 4);
    e += (float)(_Float16)celu_f(acc3[mt][0] + bb.x) * wv.x
       + (float)(_Float16)celu_f(acc3[mt][1] + bb.y) * wv.y
       + (float)(_Float16)celu_f(acc3[mt][2] + bb.z) * wv.z
       + (float)(_Float16)celu_f(acc3[mt][3] + bb.w) * wv.w;
  }
  e += __shfl_xor(e, 16, 64);
  e += __shfl_xor(e, 32, 64);              // lanes sharing l15 now hold the atom's dot
  e = (lane < 16 && valid) ? (e + pb4[s]) : 0.f;
#pragma unroll
  for (int off = 1; off < 64; off <<= 1) e += __shfl_xor(e, off, 64);
  if (lane == 0) RED[wav] = e;
  __syncthreads();
  if (tid == 0) {
    float t = 0.f;
#pragma unroll
    for (int i = 0; i < 8; ++i) t += RED[i];
    atomicAdd(out, t);
  }
}

extern "C" void kernel_launch(void* const* d_in, const int* in_sizes, int n_in,
                              void* d_out, int out_size, void* d_ws, size_t ws_size,
                              hipStream_t stream) {
  (void)n_in; (void)d_ws; (void)ws_size; (void)out_size;
  const float* aev = (const float*)d_in[0];
  const float* W1  = (const float*)d_in[1];
  const float* b1  = (const float*)d_in[2];
  const float* W2  = (const float*)d_in[3];
  const float* b2  = (const float*)d_in[4];
  const float* W3  = (const float*)d_in[5];
  const float* b3  = (const float*)d_in[6];
  const float* W4  = (const float*)d_in[7];
  const float* b4  = (const float*)d_in[8];
  const int* iH = (const int*)d_in[9];
  const int* iC = (const int*)d_in[10];
  const int* iN = (const int*)d_in[11];
  const int* iO = (const int*)d_in[12];
  const int chunk = in_sizes[9];

  constexpr int TOT = NSP * (AEV * H1N + H1N * H2N + H2N * H3N);  // 376832 = 1472*256
  prep<<<TOT / 256, 256, 0, stream>>>(W1, W2, W3, (float*)d_out);

  const int tiles = (chunk + 127) / 128;
  fused_mlp<<<dim3(tiles, NSP), 512, 0, stream>>>(aev, b1, b2, b3, W4, b4,
                                                  iH, iC, iN, iO, chunk, (float*)d_out);
}